// Round 7
// baseline (147.968 us; speedup 1.0000x reference)
//
#include <hip/hip_runtime.h>
#include <hip/hip_bf16.h>

// DynamicConv1dTBC: T=2048 B=4 C=1024 H=16 K=15 PAD_L=14 (causal)
// out[t,b,h*64+r] = sum_k softmax_k(x[t,b,:]·Wlin[h*15+k,:]) * x[t+k-14,b,h*64+r]
//
// K1: logits GEMM (M=8192,K=1024) N-split x2 (8 nt-tiles/block, heads 0-7 or
//     8-15), split-K x4 over waves, 33KB LDS -> 4 blocks/CU. w out as bf16.
// K2: depthwise conv, register-window scalar kernel (R4-proven), bf16 w.

#define T_DIM 2048
#define B_DIM 4
#define C_DIM 1024
#define H_DIM 16
#define K_TAPS 15
#define R_DIM 64
#define N_DIM 240
#define M_DIM (T_DIM * B_DIM)    // 8192
#define SM_STRIDE 132            // 128 cols + 4 pad (scatter 2-way, free)

typedef __attribute__((ext_vector_type(8))) short bf16x8;
typedef __attribute__((ext_vector_type(4))) float f32x4;

__device__ __forceinline__ unsigned short f2bf(float f) {
    union { float f; unsigned u; } v; v.f = f;
    return (unsigned short)((v.u + 0x7FFFu + ((v.u >> 16) & 1u)) >> 16);
}
__device__ __forceinline__ float bf2f(unsigned short h) {
    union { unsigned u; float f; } v; v.u = ((unsigned)h) << 16;
    return v.f;
}

// ---------------- Kernel 0: convert Wlin (240x1024 fp32) -> bf16 ------------
__global__ __launch_bounds__(256) void convert_w(
    const float* __restrict__ W, unsigned short* __restrict__ Wbf)
{
    int i = (blockIdx.x * 256 + threadIdx.x) * 4;   // grid covers 245760 elems
    float4 v = *reinterpret_cast<const float4*>(W + i);
    ushort4 o;
    o.x = f2bf(v.x); o.y = f2bf(v.y); o.z = f2bf(v.z); o.w = f2bf(v.w);
    *reinterpret_cast<ushort4*>(Wbf + i) = o;
}

// ---------------- Kernel 1: GEMM half-N + softmax, w out bf16 ---------------
// grid (M/16, 2). Block: 4 waves, split-K x4 (wave wv: k in [wv*256,(wv+1)*256)).
// nh=0: nt tiles 0..7 (cols 0..127, heads 0..7 use 0..119)
// nh=1: nt tiles 7..14 (cols 112..239, heads 8..15 use 120..239)
__global__ __launch_bounds__(256, 4) void gemm_softmax_half(
    const float* __restrict__ x, const unsigned short* __restrict__ Wbf,
    unsigned short* __restrict__ wout)
{
    __shared__ float sm[4][16][SM_STRIDE];   // 33 KB

    const int tid = threadIdx.x;
    const int wv  = tid >> 6;          // K-slice 0..3
    const int l   = tid & 63;
    const int m0  = blockIdx.x * 16;
    const int nh  = blockIdx.y;        // 0/1
    const int ntb = nh * 7;            // first nt tile
    const int row = l & 15;
    const int kg  = l >> 4;

    f32x4 acc[8];
    #pragma unroll
    for (int nt = 0; nt < 8; ++nt) acc[nt] = (f32x4){0.f, 0.f, 0.f, 0.f};

    const float* xp = x + (size_t)(m0 + row) * C_DIM + wv * 256 + kg * 8;
    const unsigned short* wp = Wbf + (size_t)(ntb * 16 + row) * C_DIM + wv * 256 + kg * 8;

    #pragma unroll 2
    for (int ks = 0; ks < 8; ++ks) {
        const int k = ks * 32;
        float4 a0 = *reinterpret_cast<const float4*>(xp + k);
        float4 a1 = *reinterpret_cast<const float4*>(xp + k + 4);
        bf16x8 bfr[8];
        #pragma unroll
        for (int nt = 0; nt < 8; ++nt)
            bfr[nt] = *reinterpret_cast<const bf16x8*>(wp + (size_t)nt * 16 * C_DIM + k);
        bf16x8 af;
        af[0] = (short)f2bf(a0.x); af[1] = (short)f2bf(a0.y);
        af[2] = (short)f2bf(a0.z); af[3] = (short)f2bf(a0.w);
        af[4] = (short)f2bf(a1.x); af[5] = (short)f2bf(a1.y);
        af[6] = (short)f2bf(a1.z); af[7] = (short)f2bf(a1.w);
        #pragma unroll
        for (int nt = 0; nt < 8; ++nt)
            acc[nt] = __builtin_amdgcn_mfma_f32_16x16x32_bf16(af, bfr[nt], acc[nt], 0, 0, 0);
    }

    // scatter partials (m89-verified D layout: m-row = kg*4+j, n = nt*16+row)
    #pragma unroll
    for (int nt = 0; nt < 8; ++nt)
        #pragma unroll
        for (int j = 0; j < 4; ++j)
            sm[wv][kg * 4 + j][nt * 16 + row] = acc[nt][j];
    __syncthreads();

    // reduce 4 K-slices + softmax: 128 threads = 16 rows x 8 heads
    if (tid < 128) {
        const int rr = tid >> 3;           // 0..15
        const int hh = tid & 7;            // 0..7 (local head)
        const int base = (nh ? 8 : 0) + hh * K_TAPS;   // local col of tap 0
        float s[K_TAPS];
        #pragma unroll
        for (int kk = 0; kk < K_TAPS; ++kk) {
            const int c = base + kk;
            s[kk] = sm[0][rr][c] + sm[1][rr][c] + sm[2][rr][c] + sm[3][rr][c];
        }
        float mx = s[0];
        #pragma unroll
        for (int kk = 1; kk < K_TAPS; ++kk) mx = fmaxf(mx, s[kk]);
        float sum = 0.f;
        #pragma unroll
        for (int kk = 0; kk < K_TAPS; ++kk) { s[kk] = __expf(s[kk] - mx); sum += s[kk]; }
        const float inv = 1.f / sum;
        unsigned short* dst = wout + (size_t)(m0 + rr) * N_DIM + (nh * 8 + hh) * K_TAPS;
        #pragma unroll
        for (int kk = 0; kk < K_TAPS; ++kk) dst[kk] = f2bf(s[kk] * inv);
    }
}

// ---------------- Kernel 2: depthwise causal conv (register window) ---------
// grid = (T/64, B*H); block 256. Stage x[t0-14 .. t0+63, b, h*64 .. +63] in LDS,
// each thread keeps its 31 x-values in registers (16 outputs x 15 taps).
__global__ __launch_bounds__(256) void conv_kernel(
    const float* __restrict__ x, const unsigned short* __restrict__ wbuf,
    float* __restrict__ out)
{
    __shared__ float xs[64 + K_TAPS - 1][R_DIM];   // 78 x 64 = 20 KB

    const int tid = threadIdx.x;
    const int t0 = blockIdx.x * 64;
    const int bh = blockIdx.y;
    const int b = bh >> 4;          // bh = b*16 + h
    const int h = bh & 15;
    const int cbase = h * R_DIM;

    // stage with float4 (78 rows x 16 quads)
    for (int idx = tid; idx < (64 + K_TAPS - 1) * 16; idx += 256) {
        int rrow = idx >> 4, q = idx & 15;
        int t = t0 - (K_TAPS - 1) + rrow;
        float4 v = (t >= 0)
            ? *reinterpret_cast<const float4*>(x + ((size_t)t * B_DIM + b) * C_DIM + cbase + q * 4)
            : (float4){0.f, 0.f, 0.f, 0.f};
        *reinterpret_cast<float4*>(&xs[rrow][q * 4]) = v;
    }
    __syncthreads();

    const int r = tid & 63;
    const int tg = __builtin_amdgcn_readfirstlane(tid >> 6);   // wave-uniform 0..3

    float xv[31];
    #pragma unroll
    for (int j = 0; j < 31; ++j) xv[j] = xs[tg * 16 + j][r];

    float accv[16];
    #pragma unroll
    for (int i = 0; i < 16; ++i) accv[i] = 0.f;

    #pragma unroll
    for (int i = 0; i < 16; ++i) {
        const int t = t0 + tg * 16 + i;                        // wave-uniform
        const unsigned short* wv = wbuf + ((size_t)t * B_DIM + b) * N_DIM + h * K_TAPS;
        #pragma unroll
        for (int k = 0; k < K_TAPS; ++k)
            accv[i] += bf2f(wv[k]) * xv[i + k];
    }

    #pragma unroll
    for (int i = 0; i < 16; ++i) {
        const int t = t0 + tg * 16 + i;
        out[((size_t)t * B_DIM + b) * C_DIM + cbase + r] = accv[i];
    }
}

extern "C" void kernel_launch(void* const* d_in, const int* in_sizes, int n_in,
                              void* d_out, int out_size, void* d_ws, size_t ws_size,
                              hipStream_t stream) {
    const float* x    = (const float*)d_in[0];   // (T,B,C) fp32
    const float* Wlin = (const float*)d_in[1];   // (240,1024) fp32
    float* out = (float*)d_out;                  // (T,B,C) fp32

    // ws: [wout bf16 8192*240 = 3.93 MB][Wbf bf16 240*1024 = 0.49 MB]
    unsigned short* wout = (unsigned short*)d_ws;
    unsigned short* Wbf  = (unsigned short*)((char*)d_ws + (size_t)M_DIM * N_DIM * sizeof(unsigned short));

    convert_w<<<(N_DIM * C_DIM) / (256 * 4), 256, 0, stream>>>(Wlin, Wbf);
    gemm_softmax_half<<<dim3(M_DIM / 16, 2), 256, 0, stream>>>(x, Wbf, wout);
    conv_kernel<<<dim3(T_DIM / 64, B_DIM * H_DIM), 256, 0, stream>>>(x, wout, out);
}

// Round 8
// 143.741 us; speedup vs baseline: 1.0294x; 1.0294x over previous
//
#include <hip/hip_runtime.h>
#include <hip/hip_bf16.h>

// DynamicConv1dTBC: T=2048 B=4 C=1024 H=16 K=15 PAD_L=14 (causal)
// out[t,b,h*64+r] = sum_k softmax_k(x[t,b,:]·Wlin[h*15+k,:]) * x[t+k-14,b,h*64+r]
//
// K1 (gemm_softmax_v3): streaming-pipeline GEMM M=8192,K=1024,N=240.
//   grid=256 (1 block/CU), 128 thr = 2 waves, BM=32, BK=128, 8 K-steps.
//   global_load_lds depth-2 prefetch, 3 LDS buffers, counted vmcnt(8) barriers.
//   XOR chunk swizzle: linear LDS dest + pre-swizzled global src + swz read.
//   Epilogue: per-wave softmax, w out fp32 padded [m][H][16].
// K2 (conv): R4-proven register-window conv, scalar uniform w-loads.

#define T_DIM 2048
#define B_DIM 4
#define C_DIM 1024
#define H_DIM 16
#define K_TAPS 15
#define R_DIM 64
#define N_DIM 240
#define M_DIM 8192
#define BM 32
#define BKF 128                  // floats per K-step
#define NSTEP 8                  // 1024 / 128
#define TILE_F (BM * BKF)        // 4096 floats = 16 KB
#define EP_STRIDE 244

typedef __attribute__((ext_vector_type(8))) short bf16x8;
typedef __attribute__((ext_vector_type(4))) float f32x4;

__device__ __forceinline__ unsigned short f2bf(float f) {
    union { float f; unsigned u; } v; v.f = f;
    return (unsigned short)((v.u + 0x7FFFu + ((v.u >> 16) & 1u)) >> 16);
}

typedef __attribute__((address_space(1))) const void g_void;
typedef __attribute__((address_space(3))) void l_void;
__device__ __forceinline__ void gload_lds16(const void* g, void* l) {
    __builtin_amdgcn_global_load_lds((g_void*)g, (l_void*)l, 16, 0, 0);
}

// ---------------- Kernel 0: convert Wlin (240x1024 fp32) -> bf16 ------------
__global__ __launch_bounds__(256) void convert_w(
    const float* __restrict__ W, unsigned short* __restrict__ Wbf)
{
    int i = (blockIdx.x * 256 + threadIdx.x) * 4;
    float4 v = *reinterpret_cast<const float4*>(W + i);
    ushort4 o;
    o.x = f2bf(v.x); o.y = f2bf(v.y); o.z = f2bf(v.z); o.w = f2bf(v.w);
    *reinterpret_cast<ushort4*>(Wbf + i) = o;
}

// ---------------- Kernel 1: streaming MFMA GEMM + softmax -------------------
// Stage tile (32 rows x 128 floats) for K-step s into linear LDS buf.
// LDS chunk c (16B) of row r holds GLOBAL chunk c ^ (r&7)  (XOR involution).
__device__ __forceinline__ void stage_tile(const float* xrow0, int s, float* buf, int tid) {
    #pragma unroll
    for (int j = 0; j < 8; ++j) {
        const int e  = j * 128 + tid;      // 0..1023 (chunk index in tile)
        const int r  = e >> 5;             // row 0..31
        const int c  = e & 31;             // lds chunk within row
        const int gc = c ^ (r & 7);        // pre-swizzled source chunk
        const float* src = xrow0 + (size_t)r * C_DIM + s * BKF + gc * 4;
        float* dst = buf + (size_t)(j * 128 + (tid & ~63)) * 4;  // wave-uniform base
        gload_lds16(src, dst);
    }
}

__global__ __launch_bounds__(128) void gemm_softmax_v3(
    const float* __restrict__ x, const unsigned short* __restrict__ Wbf,
    float* __restrict__ wout)
{
    __shared__ float smem[3 * TILE_F];   // 48 KB staging; epilogue overlays

    const int tid = threadIdx.x;
    const int wv  = tid >> 6;            // wave 0/1 -> rows wv*16..wv*16+15
    const int l   = tid & 63;
    const int m0  = blockIdx.x * BM;
    const int row = l & 15;
    const int kg  = l >> 4;              // 0..3
    const int r7  = row & 7;

    const float* xrow0 = x + (size_t)m0 * C_DIM;
    const unsigned short* wp = Wbf + (size_t)row * C_DIM + kg * 8;

    f32x4 acc[15];
    #pragma unroll
    for (int nt = 0; nt < 15; ++nt) acc[nt] = (f32x4){0.f, 0.f, 0.f, 0.f};

    // prologue: prefetch tiles 0,1
    stage_tile(xrow0, 0, smem + 0 * TILE_F, tid);
    stage_tile(xrow0, 1, smem + 1 * TILE_F, tid);
    asm volatile("s_waitcnt vmcnt(8)" ::: "memory");   // tile0 done; tile1 in flight
    __builtin_amdgcn_s_barrier();

    #pragma unroll
    for (int s = 0; s < NSTEP; ++s) {
        const float* abase = smem + (s % 3) * TILE_F + (size_t)(wv * 16 + row) * BKF;
        #pragma unroll
        for (int sub = 0; sub < 4; ++sub) {
            const int cb = sub * 8 + kg * 2;
            // frag floats [sub*32+kg*8 .. +7] live at lds chunks (cb^r7),(cb+1)^r7
            float4 a0 = *reinterpret_cast<const float4*>(abase + (size_t)((cb + 0) ^ r7) * 4);
            float4 a1 = *reinterpret_cast<const float4*>(abase + (size_t)((cb + 1) ^ r7) * 4);
            bf16x8 af;
            af[0] = (short)f2bf(a0.x); af[1] = (short)f2bf(a0.y);
            af[2] = (short)f2bf(a0.z); af[3] = (short)f2bf(a0.w);
            af[4] = (short)f2bf(a1.x); af[5] = (short)f2bf(a1.y);
            af[6] = (short)f2bf(a1.z); af[7] = (short)f2bf(a1.w);
            const int kofs = s * BKF + sub * 32;
            #pragma unroll
            for (int nt = 0; nt < 15; ++nt) {
                bf16x8 bfv = *reinterpret_cast<const bf16x8*>(wp + (size_t)nt * 16 * C_DIM + kofs);
                acc[nt] = __builtin_amdgcn_mfma_f32_16x16x32_bf16(af, bfv, acc[nt], 0, 0, 0);
            }
        }
        __builtin_amdgcn_sched_barrier(0);   // keep stage issue AFTER B-loads (in-order vmcnt)
        if (s + 2 < NSTEP)
            stage_tile(xrow0, s + 2, smem + ((s + 2) % 3) * TILE_F, tid);
        if (s < NSTEP - 2) { asm volatile("s_waitcnt vmcnt(8)" ::: "memory"); }
        else               { asm volatile("s_waitcnt vmcnt(0)" ::: "memory"); }
        __builtin_amdgcn_s_barrier();
    }
    __syncthreads();   // all MFMA/ds reads done before overlaying staging LDS

    // epilogue: scatter logits (D: m-row = kg*4+j, n-col = nt*16+row; m89 layout)
    float* ep = smem + (size_t)wv * (16 * EP_STRIDE);
    #pragma unroll
    for (int nt = 0; nt < 15; ++nt)
        #pragma unroll
        for (int j = 0; j < 4; ++j)
            ep[(kg * 4 + j) * EP_STRIDE + nt * 16 + row] = acc[nt][j];
    __syncthreads();

    // softmax: each lane handles 4 (row,head) pairs of its own wave's 16 rows
    #pragma unroll
    for (int p = 0; p < 4; ++p) {
        const int idx = p * 64 + l;
        const int rr  = idx >> 4;        // 0..15
        const int hh  = idx & 15;
        const float* sp = ep + rr * EP_STRIDE + hh * K_TAPS;
        float sv[K_TAPS];
        #pragma unroll
        for (int kk = 0; kk < K_TAPS; ++kk) sv[kk] = sp[kk];
        float mx = sv[0];
        #pragma unroll
        for (int kk = 1; kk < K_TAPS; ++kk) mx = fmaxf(mx, sv[kk]);
        float sum = 0.f;
        #pragma unroll
        for (int kk = 0; kk < K_TAPS; ++kk) { sv[kk] = __expf(sv[kk] - mx); sum += sv[kk]; }
        const float inv = 1.f / sum;
        float o[16];
        #pragma unroll
        for (int kk = 0; kk < K_TAPS; ++kk) o[kk] = sv[kk] * inv;
        o[15] = 0.f;
        float* dst = wout + ((size_t)(m0 + wv * 16 + rr)) * (H_DIM * 16) + hh * 16;
        #pragma unroll
        for (int q = 0; q < 4; ++q)
            *reinterpret_cast<float4*>(dst + q * 4) = *reinterpret_cast<const float4*>(&o[q * 4]);
    }
}

// ---------------- Kernel 2: depthwise causal conv (register window) ---------
// grid = (T/64, B*H); block 256. w rows are wave-uniform -> scalar loads.
__global__ __launch_bounds__(256) void conv_kernel(
    const float* __restrict__ x, const float* __restrict__ wbuf,
    float* __restrict__ out)
{
    __shared__ float xs[64 + K_TAPS - 1][R_DIM];   // 78 x 64 = 20 KB

    const int tid = threadIdx.x;
    const int t0 = blockIdx.x * 64;
    const int bh = blockIdx.y;
    const int b = bh >> 4;          // bh = b*16 + h
    const int h = bh & 15;
    const int cbase = h * R_DIM;

    for (int idx = tid; idx < (64 + K_TAPS - 1) * 16; idx += 256) {
        int rrow = idx >> 4, q = idx & 15;
        int t = t0 - (K_TAPS - 1) + rrow;
        float4 v = (t >= 0)
            ? *reinterpret_cast<const float4*>(x + ((size_t)t * B_DIM + b) * C_DIM + cbase + q * 4)
            : (float4){0.f, 0.f, 0.f, 0.f};
        *reinterpret_cast<float4*>(&xs[rrow][q * 4]) = v;
    }
    __syncthreads();

    const int r = tid & 63;
    const int tg = __builtin_amdgcn_readfirstlane(tid >> 6);   // wave-uniform 0..3

    float xv[31];
    #pragma unroll
    for (int j = 0; j < 31; ++j) xv[j] = xs[tg * 16 + j][r];

    float accv[16];
    #pragma unroll
    for (int i = 0; i < 16; ++i) accv[i] = 0.f;

    #pragma unroll
    for (int i = 0; i < 16; ++i) {
        const int t = t0 + tg * 16 + i;                        // wave-uniform
        const float* wrow = wbuf + ((size_t)t * B_DIM + b) * (H_DIM * 16) + h * 16;
        #pragma unroll
        for (int k = 0; k < K_TAPS; ++k)
            accv[i] += wrow[k] * xv[i + k];
    }

    #pragma unroll
    for (int i = 0; i < 16; ++i) {
        const int t = t0 + tg * 16 + i;
        out[((size_t)t * B_DIM + b) * C_DIM + cbase + r] = accv[i];
    }
}

extern "C" void kernel_launch(void* const* d_in, const int* in_sizes, int n_in,
                              void* d_out, int out_size, void* d_ws, size_t ws_size,
                              hipStream_t stream) {
    const float* x    = (const float*)d_in[0];   // (T,B,C) fp32
    const float* Wlin = (const float*)d_in[1];   // (240,1024) fp32
    float* out = (float*)d_out;                  // (T,B,C) fp32

    // ws: [wout fp32 8192*256 = 8 MB][Wbf bf16 240*1024 = 0.49 MB]
    float* wout = (float*)d_ws;
    unsigned short* Wbf = (unsigned short*)((char*)d_ws + (size_t)M_DIM * H_DIM * 16 * sizeof(float));

    convert_w<<<(N_DIM * C_DIM) / (256 * 4), 256, 0, stream>>>(Wlin, Wbf);
    gemm_softmax_v3<<<M_DIM / BM, 128, 0, stream>>>(x, Wbf, wout);
    conv_kernel<<<dim3(T_DIM / 64, B_DIM * H_DIM), 256, 0, stream>>>(x, wout, out);
}

// Round 9
// 128.695 us; speedup vs baseline: 1.1498x; 1.1169x over previous
//
#include <hip/hip_runtime.h>
#include <hip/hip_bf16.h>

// DynamicConv1dTBC: T=2048 B=4 C=1024 H=16 K=15 PAD_L=14 (causal)
// out[t,b,h*64+r] = sum_k softmax_k(x[t,b,:]·Wlin[h*15+k,:]) * x[t+k-14,b,h*64+r]
//
// K1: split-K x4 MFMA GEMM with REGISTER PING-PONG on the 15 B-fragments
//     (load sub+1 while MFMAing sub) under __launch_bounds__(256,2) so the
//     allocator has a ~256-VGPR budget (R3/R7/R8 were serialized by reg caps).
// K2: R8-proven register-window conv, uniform scalar w-loads (fp32 padded w).

#define T_DIM 2048
#define B_DIM 4
#define C_DIM 1024
#define H_DIM 16
#define K_TAPS 15
#define R_DIM 64
#define N_DIM 240
#define M_DIM 8192
#define SM_STRIDE 244            // R4-proven pad

typedef __attribute__((ext_vector_type(8))) short bf16x8;
typedef __attribute__((ext_vector_type(4))) float f32x4;

__device__ __forceinline__ unsigned short f2bf(float f) {
    union { float f; unsigned u; } v; v.f = f;
    return (unsigned short)((v.u + 0x7FFFu + ((v.u >> 16) & 1u)) >> 16);
}

// ---------------- Kernel 0: convert Wlin (240x1024 fp32) -> bf16 ------------
__global__ __launch_bounds__(256) void convert_w(
    const float* __restrict__ W, unsigned short* __restrict__ Wbf)
{
    int i = (blockIdx.x * 256 + threadIdx.x) * 4;
    float4 v = *reinterpret_cast<const float4*>(W + i);
    ushort4 o;
    o.x = f2bf(v.x); o.y = f2bf(v.y); o.z = f2bf(v.z); o.w = f2bf(v.w);
    *reinterpret_cast<ushort4*>(Wbf + i) = o;
}

// ---------------- Kernel 1: GEMM + softmax, register ping-pong --------------
// grid 512, block 256 = 4 waves. Wave wv: K-slice [wv*256, wv*256+256), 8 subs
// of K=32. Fragment layouts are the R3-verified ones (m89).
__global__ __launch_bounds__(256, 2) void gemm_softmax_mfma(
    const float* __restrict__ x, const unsigned short* __restrict__ Wbf,
    float* __restrict__ wout)
{
    __shared__ float sm[4][16][SM_STRIDE];   // 62.5 KB -> 2 blocks/CU

    const int tid = threadIdx.x;
    const int wv  = tid >> 6;          // K-slice 0..3
    const int l   = tid & 63;
    const int m0  = blockIdx.x * 16;
    const int row = l & 15;
    const int kg  = l >> 4;            // 0..3

    const float* xp = x + (size_t)(m0 + row) * C_DIM + wv * 256 + kg * 8;
    const unsigned short* wp = Wbf + (size_t)row * C_DIM + wv * 256 + kg * 8;

    f32x4 acc[15];
    #pragma unroll
    for (int nt = 0; nt < 15; ++nt) acc[nt] = (f32x4){0.f, 0.f, 0.f, 0.f};

    // prologue: sub 0 fragments
    bf16x8 bcur[15];
    #pragma unroll
    for (int nt = 0; nt < 15; ++nt)
        bcur[nt] = *reinterpret_cast<const bf16x8*>(wp + (size_t)nt * 16 * C_DIM);
    float4 ac0 = *reinterpret_cast<const float4*>(xp);
    float4 ac1 = *reinterpret_cast<const float4*>(xp + 4);

    #pragma unroll
    for (int sub = 0; sub < 8; ++sub) {
        // issue next sub's loads FIRST (independent of this sub's MFMAs)
        bf16x8 bnxt[15];
        float4 an0, an1;
        if (sub < 7) {
            const int kn = (sub + 1) * 32;
            #pragma unroll
            for (int nt = 0; nt < 15; ++nt)
                bnxt[nt] = *reinterpret_cast<const bf16x8*>(wp + (size_t)nt * 16 * C_DIM + kn);
            an0 = *reinterpret_cast<const float4*>(xp + kn);
            an1 = *reinterpret_cast<const float4*>(xp + kn + 4);
        }
        // pack current A and run 15 MFMAs
        bf16x8 af;
        af[0] = (short)f2bf(ac0.x); af[1] = (short)f2bf(ac0.y);
        af[2] = (short)f2bf(ac0.z); af[3] = (short)f2bf(ac0.w);
        af[4] = (short)f2bf(ac1.x); af[5] = (short)f2bf(ac1.y);
        af[6] = (short)f2bf(ac1.z); af[7] = (short)f2bf(ac1.w);
        #pragma unroll
        for (int nt = 0; nt < 15; ++nt)
            acc[nt] = __builtin_amdgcn_mfma_f32_16x16x32_bf16(af, bcur[nt], acc[nt], 0, 0, 0);
        if (sub < 7) {
            #pragma unroll
            for (int nt = 0; nt < 15; ++nt) bcur[nt] = bnxt[nt];
            ac0 = an0; ac1 = an1;
        }
    }

    // scatter partials (m89 D layout: m-row = kg*4+j, n-col = nt*16+row)
    #pragma unroll
    for (int nt = 0; nt < 15; ++nt)
        #pragma unroll
        for (int j = 0; j < 4; ++j)
            sm[wv][kg * 4 + j][nt * 16 + row] = acc[nt][j];
    __syncthreads();

    // reduce 4 K-slices + softmax; thread = one (row rr, head hh)
    const int rr = tid >> 4;           // 0..15
    const int hh = tid & 15;           // 0..15
    float s[K_TAPS];
    #pragma unroll
    for (int kk = 0; kk < K_TAPS; ++kk) {
        const int c = hh * K_TAPS + kk;
        s[kk] = sm[0][rr][c] + sm[1][rr][c] + sm[2][rr][c] + sm[3][rr][c];
    }
    float mx = s[0];
    #pragma unroll
    for (int kk = 1; kk < K_TAPS; ++kk) mx = fmaxf(mx, s[kk]);
    float sum = 0.f;
    #pragma unroll
    for (int kk = 0; kk < K_TAPS; ++kk) { s[kk] = __expf(s[kk] - mx); sum += s[kk]; }
    const float inv = 1.f / sum;
    float o[16];
    #pragma unroll
    for (int kk = 0; kk < K_TAPS; ++kk) o[kk] = s[kk] * inv;
    o[15] = 0.f;
    // padded fp32 layout [m][16 heads][16]
    float* dst = wout + ((size_t)(m0 + rr)) * (H_DIM * 16) + hh * 16;
    #pragma unroll
    for (int q = 0; q < 4; ++q)
        *reinterpret_cast<float4*>(dst + q * 4) = *reinterpret_cast<const float4*>(&o[q * 4]);
}

// ---------------- Kernel 2: depthwise causal conv (register window) ---------
// grid = (T/64, B*H); block 256. w rows are wave-uniform -> scalar loads.
__global__ __launch_bounds__(256) void conv_kernel(
    const float* __restrict__ x, const float* __restrict__ wbuf,
    float* __restrict__ out)
{
    __shared__ float xs[64 + K_TAPS - 1][R_DIM];   // 78 x 64 = 20 KB

    const int tid = threadIdx.x;
    const int t0 = blockIdx.x * 64;
    const int bh = blockIdx.y;
    const int b = bh >> 4;          // bh = b*16 + h
    const int h = bh & 15;
    const int cbase = h * R_DIM;

    for (int idx = tid; idx < (64 + K_TAPS - 1) * 16; idx += 256) {
        int rrow = idx >> 4, q = idx & 15;
        int t = t0 - (K_TAPS - 1) + rrow;
        float4 v = (t >= 0)
            ? *reinterpret_cast<const float4*>(x + ((size_t)t * B_DIM + b) * C_DIM + cbase + q * 4)
            : (float4){0.f, 0.f, 0.f, 0.f};
        *reinterpret_cast<float4*>(&xs[rrow][q * 4]) = v;
    }
    __syncthreads();

    const int r = tid & 63;
    const int tg = __builtin_amdgcn_readfirstlane(tid >> 6);   // wave-uniform 0..3

    float xv[31];
    #pragma unroll
    for (int j = 0; j < 31; ++j) xv[j] = xs[tg * 16 + j][r];

    float accv[16];
    #pragma unroll
    for (int i = 0; i < 16; ++i) accv[i] = 0.f;

    #pragma unroll
    for (int i = 0; i < 16; ++i) {
        const int t = t0 + tg * 16 + i;                        // wave-uniform
        const float* wrow = wbuf + ((size_t)t * B_DIM + b) * (H_DIM * 16) + h * 16;
        #pragma unroll
        for (int k = 0; k < K_TAPS; ++k)
            accv[i] += wrow[k] * xv[i + k];
    }

    #pragma unroll
    for (int i = 0; i < 16; ++i) {
        const int t = t0 + tg * 16 + i;
        out[((size_t)t * B_DIM + b) * C_DIM + cbase + r] = accv[i];
    }
}

extern "C" void kernel_launch(void* const* d_in, const int* in_sizes, int n_in,
                              void* d_out, int out_size, void* d_ws, size_t ws_size,
                              hipStream_t stream) {
    const float* x    = (const float*)d_in[0];   // (T,B,C) fp32
    const float* Wlin = (const float*)d_in[1];   // (240,1024) fp32
    float* out = (float*)d_out;                  // (T,B,C) fp32

    // ws: [wout fp32 8192*256 = 8 MB][Wbf bf16 240*1024 = 0.49 MB]
    float* wout = (float*)d_ws;
    unsigned short* Wbf = (unsigned short*)((char*)d_ws + (size_t)M_DIM * H_DIM * 16 * sizeof(float));

    convert_w<<<(N_DIM * C_DIM) / (256 * 4), 256, 0, stream>>>(Wlin, Wbf);
    gemm_softmax_mfma<<<M_DIM / 16, 256, 0, stream>>>(x, Wbf, wout);
    conv_kernel<<<dim3(T_DIM / 64, B_DIM * H_DIM), 256, 0, stream>>>(x, wout, out);
}